// Round 11
// baseline (461.537 us; speedup 1.0000x reference)
//
#include <hip/hip_runtime.h>
#include <stdint.h>

#define M_DIM 8192
#define K_DIM 4096
#define N_DIM 4096
#define KTILES (K_DIM / 64)

typedef __attribute__((ext_vector_type(4))) int i32x4;

// ---------------------------------------------------------------------------
// Pack int32-stored int8 weights [N,K] -> true int8 [N,K]; per-row sum folded
// into integer correction corr[n] = (128 - zp) * rowsum[n].
// ---------------------------------------------------------------------------
__global__ void pack_w_kernel(const int* __restrict__ w, char* __restrict__ wp,
                              int* __restrict__ corr, const int* __restrict__ zpp) {
  __shared__ int red[256];
  const int n = blockIdx.x;
  const int t = threadIdx.x;
  const int4* row = (const int4*)(w + (size_t)n * K_DIM);
  int s = 0;
  int words[4];
#pragma unroll
  for (int u = 0; u < 4; ++u) {
    int4 v = row[t * 4 + u];
    s += v.x + v.y + v.z + v.w;
    words[u] = (v.x & 255) | ((v.y & 255) << 8) | ((v.z & 255) << 16) | (v.w << 24);
  }
  ((int4*)(wp + (size_t)n * K_DIM))[t] = make_int4(words[0], words[1], words[2], words[3]);
  red[t] = s;
  __syncthreads();
  for (int off = 128; off > 0; off >>= 1) {
    if (t < off) red[t] += red[t + off];
    __syncthreads();
  }
  if (t == 0) corr[n] = (128 - zpp[0]) * red[0];
}

// ---------------------------------------------------------------------------
// Quantize fp32 input -> int8 (q - 128), 4 elements/thread.
// ---------------------------------------------------------------------------
__global__ void quant_in_kernel(const float* __restrict__ x, char* __restrict__ q,
                                const float* __restrict__ sp, const int* __restrict__ zpp) {
  const int i = blockIdx.x * blockDim.x + threadIdx.x;
  const float s = sp[0];
  const float zp = (float)zpp[0];
  float4 v = ((const float4*)x)[i];
  float t0 = fminf(fmaxf(rintf(v.x / s) + zp, 0.f), 255.f);
  float t1 = fminf(fmaxf(rintf(v.y / s) + zp, 0.f), 255.f);
  float t2 = fminf(fmaxf(rintf(v.z / s) + zp, 0.f), 255.f);
  float t3 = fminf(fmaxf(rintf(v.w / s) + zp, 0.f), 255.f);
  int b0 = (int)t0 - 128, b1 = (int)t1 - 128, b2 = (int)t2 - 128, b3 = (int)t3 - 128;
  ((int*)q)[i] = (b0 & 255) | ((b1 & 255) << 8) | ((b2 & 255) << 16) | (b3 << 24);
}

// ---------------------------------------------------------------------------
// 256x256 i8 GEMM = R3 schedule (best: 135.5us, MfmaUtil 46, 0 conflicts)
// + R9-validated packed epilogue (B content permutation; WRITE_SIZE = 32MB)
// + XCD-aware block swizzle (each XCD's 32 concurrent blocks share ONE 1MB
//   B-panel -> L2-resident) + register ping-pong (2-body alternation kills
//   the 32 v_mov/tile/wave copy tax; frag regs unchanged at 80).
// Geometry: 512 thr = 8 waves (2M x 4N), per-wave 128x64, BK=64 B,
// mfma_i32_16x16x64_i8, 32 MFMA/wave/tile in two 16-clusters (shared B).
// Ring/ledger (R3-proven): 4-slot ring (A16K+B16K)=128KB, prefetch dist 3;
// slots t,t+1 confirmed at tile-t start; vmcnt(4)/tile confirms t+2;
// barrier separates a slot's last reads from its overwrite.
// Swizzle (0-conflict): phys 16B slot = g ^ ((row>>1)&3) on staging source
// and ds_read addr. B permutation: LDS row rho holds weight row
// (rho&~63)+4*(rho&15)+((rho>>4)&3) -> epilogue n = base+4c+j consecutive.
// ---------------------------------------------------------------------------
#define STAGE16(SRC, DST)                                                     \
  __builtin_amdgcn_global_load_lds(                                           \
      (const __attribute__((address_space(1))) void*)(SRC),                   \
      (__attribute__((address_space(3))) void*)(DST), 16, 0, 0)

#define RD(p) (*(const i32x4*)(p))

// CA/CB: current tile frags (consumed). NA/NB: next tile frags (produced).
#define TILE_PP(SLOT, KSTG, CA, CB, NA, NB, DO_NEXT)                          \
  {                                                                           \
    const char* bufA_ = &lds[SLOT][0][0];                                     \
    char* nA_ = &lds[((SLOT) + 3) & 3][0][0];                                 \
    char* nB_ = &lds[((SLOT) + 3) & 3][1][0];                                 \
    i32x4 a1_[4];                                                             \
    _Pragma("unroll") for (int i_ = 0; i_ < 4; ++i_)                          \
        a1_[i_] = RD(bufA_ + aoff[4 + i_]);                                   \
    STAGE16(asrc0 + (size_t)(KSTG), nA_ + o0_);                               \
    STAGE16(asrc1 + (size_t)(KSTG), nA_ + o1_);                               \
    __builtin_amdgcn_s_setprio(1);                                            \
    _Pragma("unroll") for (int i_ = 0; i_ < 4; ++i_)                          \
        _Pragma("unroll") for (int j_ = 0; j_ < 4; ++j_)                      \
            acc[i_][j_] = __builtin_amdgcn_mfma_i32_16x16x64_i8(              \
                CA[i_], CB[j_], acc[i_][j_], 0, 0, 0);                        \
    __builtin_amdgcn_s_setprio(0);                                            \
    if (DO_NEXT) {                                                            \
      const char* xA_ = &lds[((SLOT) + 1) & 3][0][0];                         \
      const char* xB_ = &lds[((SLOT) + 1) & 3][1][0];                         \
      _Pragma("unroll") for (int i_ = 0; i_ < 4; ++i_)                        \
          NA[i_] = RD(xA_ + aoff[i_]);                                        \
      _Pragma("unroll") for (int j_ = 0; j_ < 4; ++j_)                        \
          NB[j_] = RD(xB_ + boff[j_]);                                        \
    }                                                                         \
    STAGE16(bsrc0 + (size_t)(KSTG), nB_ + o0_);                               \
    STAGE16(bsrc1 + (size_t)(KSTG), nB_ + o1_);                               \
    __builtin_amdgcn_s_setprio(1);                                            \
    _Pragma("unroll") for (int i_ = 0; i_ < 4; ++i_)                          \
        _Pragma("unroll") for (int j_ = 0; j_ < 4; ++j_)                      \
            acc[4 + i_][j_] = __builtin_amdgcn_mfma_i32_16x16x64_i8(          \
                a1_[i_], CB[j_], acc[4 + i_][j_], 0, 0, 0);                   \
    __builtin_amdgcn_s_setprio(0);                                            \
    asm volatile("s_waitcnt vmcnt(4)" ::: "memory");                          \
    __builtin_amdgcn_s_barrier();                                             \
  }

template <int WRITE_Q>
__global__ __launch_bounds__(512, 2) void gemm_kernel(
    const char* __restrict__ qa, const char* __restrict__ wb,
    const int* __restrict__ corr, const float* __restrict__ swp,
    const float* __restrict__ bias, const float* __restrict__ sp,
    const int* __restrict__ zpp, char* __restrict__ outq, float* __restrict__ outf) {
  __shared__ __align__(16) char lds[4][2][16384];  // 128 KB: 4-slot ring
  const int tid = threadIdx.x;
  const int lane = tid & 63;
  const int w = tid >> 6;
  const int wr = w >> 2;   // 0..1 (M)
  const int wc = w & 3;    // 0..3 (N)
  // XCD-aware swizzle: 512 blocks, 8 XCDs, 64 per XCD (bijective, 512%8==0).
  // XCD k runs logical wg [64k, 64k+63] -> 32 concurrent blocks share one
  // bn-panel pair (B-panel 1MB, L2-resident).
  const int bid0 = blockIdx.x;
  const int bid = (bid0 & 7) * 64 + (bid0 >> 3);
  const int bm = bid & 31;  // M/256 = 32, fastest: neighbors share B panel
  const int bn = bid >> 5;  // N/256 = 16
  const char* abase = qa + (size_t)bm * 256 * K_DIM;
  const char* bbase = wb + (size_t)bn * 256 * K_DIM;

  // --- per-thread staging constants (inverse-swizzled global sources) ---
  const int o0_ = tid * 16;
  const int o1_ = 8192 + tid * 16;
  const int r0_ = o0_ >> 6, r1_ = o1_ >> 6;
  const int g0_ = ((o0_ >> 4) & 3) ^ ((r0_ >> 1) & 3);
  const int g1_ = ((o1_ >> 4) & 3) ^ ((r1_ >> 1) & 3);
  const char* asrc0 = abase + (size_t)r0_ * K_DIM + g0_ * 16;
  const char* asrc1 = abase + (size_t)r1_ * K_DIM + g1_ * 16;
  // B content permutation: LDS row rho holds weight row (rho&~63)+4*(rho&15)+((rho>>4)&3)
  const int p0_ = (r0_ & ~63) + 4 * (r0_ & 15) + ((r0_ >> 4) & 3);
  const int p1_ = (r1_ & ~63) + 4 * (r1_ & 15) + ((r1_ >> 4) & 3);
  const char* bsrc0 = bbase + (size_t)p0_ * K_DIM + g0_ * 16;
  const char* bsrc1 = bbase + (size_t)p1_ * K_DIM + g1_ * 16;

  // --- per-thread ds_read byte offsets (swizzled) ---
  const int rr = lane & 15;
  const int g = lane >> 4;
  int aoff[8], boff[4];
#pragma unroll
  for (int i = 0; i < 8; ++i) {
    const int row = wr * 128 + i * 16 + rr;
    aoff[i] = (row << 6) + ((g ^ ((row >> 1) & 3)) << 4);
  }
#pragma unroll
  for (int j = 0; j < 4; ++j) {
    const int row = wc * 64 + j * 16 + rr;
    boff[j] = (row << 6) + ((g ^ ((row >> 1) & 3)) << 4);
  }

  i32x4 acc[8][4] = {};

  // --- prologue: stage slots 0,1,2 (tiles 0,1,2); confirm slots 0 AND 1 ---
  STAGE16(asrc0, &lds[0][0][o0_]); STAGE16(asrc1, &lds[0][0][o1_]);
  STAGE16(bsrc0, &lds[0][1][o0_]); STAGE16(bsrc1, &lds[0][1][o1_]);
  STAGE16(asrc0 + 64, &lds[1][0][o0_]); STAGE16(asrc1 + 64, &lds[1][0][o1_]);
  STAGE16(bsrc0 + 64, &lds[1][1][o0_]); STAGE16(bsrc1 + 64, &lds[1][1][o1_]);
  STAGE16(asrc0 + 128, &lds[2][0][o0_]); STAGE16(asrc1 + 128, &lds[2][0][o1_]);
  STAGE16(bsrc0 + 128, &lds[2][1][o0_]); STAGE16(bsrc1 + 128, &lds[2][1][o1_]);
  asm volatile("s_waitcnt vmcnt(4)" ::: "memory");  // slots 0,1 confirmed
  __builtin_amdgcn_s_barrier();

  i32x4 aA[4], bA[4], aB[4], bB[4];  // ping-pong frag sets
#pragma unroll
  for (int i = 0; i < 4; ++i) aA[i] = RD(&lds[0][0][0] + aoff[i]);
#pragma unroll
  for (int j = 0; j < 4; ++j) bA[j] = RD(&lds[0][1][0] + boff[j]);

  // --- main loop: tiles 0..59 in blocks of 4, alternating frag sets ---
  for (int tb = 0; tb < (KTILES - 4) / 4; ++tb) {
    const int t0 = tb * 4;
    TILE_PP(0, (size_t)(t0 + 3) * 64, aA, bA, aB, bB, 1)
    TILE_PP(1, (size_t)(t0 + 4) * 64, aB, bB, aA, bA, 1)
    TILE_PP(2, (size_t)(t0 + 5) * 64, aA, bA, aB, bB, 1)
    TILE_PP(3, (size_t)(t0 + 6) * 64, aB, bB, aA, bA, 1)
  }
  // --- peeled tail: tiles 60..63; stage clamps to 63 (dead re-stage) ---
  TILE_PP(0, (size_t)(KTILES - 1) * 64, aA, bA, aB, bB, 1)
  TILE_PP(1, (size_t)(KTILES - 1) * 64, aB, bB, aA, bA, 1)
  TILE_PP(2, (size_t)(KTILES - 1) * 64, aA, bA, aB, bB, 1)
  TILE_PP(3, (size_t)(KTILES - 1) * 64, aB, bB, aA, bA, 0)
  asm volatile("s_waitcnt vmcnt(0)" ::: "memory");  // drain before exit

  // --- epilogue (R9-validated): frag j, lane c -> n = nb4 + j ---
  const float s = sp[0];
  const float zpf = (float)zpp[0];
  const int m0 = bm * 256 + wr * 128 + (lane >> 4) * 4;
  const int nb4 = bn * 256 + wc * 64 + ((lane & 15) << 2);
  const int4 cr4 = *(const int4*)(corr + nb4);
  const float4 sw4 = *(const float4*)(swp + nb4);
  const float4 bb4 = *(const float4*)(bias + nb4);
  const float fs0 = s * sw4.x, fs1 = s * sw4.y, fs2 = s * sw4.z, fs3 = s * sw4.w;
#pragma unroll
  for (int i = 0; i < 8; ++i) {
#pragma unroll
    for (int q = 0; q < 4; ++q) {
      const int m = m0 + i * 16 + q;
      const float v0 = fs0 * (float)(acc[i][0][q] + cr4.x) + bb4.x;
      const float v1 = fs1 * (float)(acc[i][1][q] + cr4.y) + bb4.y;
      const float v2 = fs2 * (float)(acc[i][2][q] + cr4.z) + bb4.z;
      const float v3 = fs3 * (float)(acc[i][3][q] + cr4.w) + bb4.w;
      if (WRITE_Q) {
        const int b0i = (int)fminf(fmaxf(rintf(v0 / s) + zpf, 0.f), 255.f) - 128;
        const int b1i = (int)fminf(fmaxf(rintf(v1 / s) + zpf, 0.f), 255.f) - 128;
        const int b2i = (int)fminf(fmaxf(rintf(v2 / s) + zpf, 0.f), 255.f) - 128;
        const int b3i = (int)fminf(fmaxf(rintf(v3 / s) + zpf, 0.f), 255.f) - 128;
        const uint32_t pk = (uint32_t)(b0i & 255) | ((uint32_t)(b1i & 255) << 8) |
                            ((uint32_t)(b2i & 255) << 16) | ((uint32_t)b3i << 24);
        *(uint32_t*)(outq + (size_t)m * N_DIM + nb4) = pk;
      } else {
        float4 o4;
        o4.x = v0; o4.y = v1; o4.z = v2; o4.w = v3;
        *(float4*)(outf + (size_t)m * N_DIM + nb4) = o4;
      }
    }
  }
}

// ---------------------------------------------------------------------------
extern "C" void kernel_launch(void* const* d_in, const int* in_sizes, int n_in,
                              void* d_out, int out_size, void* d_ws, size_t ws_size,
                              hipStream_t stream) {
  const float* x = (const float*)d_in[0];
  const int* wq = (const int*)d_in[1];
  const float* bias = (const float*)d_in[2];
  const float* s_in = (const float*)d_in[3];
  const int* zp_in = (const int*)d_in[4];
  const float* s_w = (const float*)d_in[5];
  float* out = (float*)d_out;

  const size_t WP_BYTES = (size_t)N_DIM * K_DIM;  // 16 MB packed int8 W
  const size_t Q_BYTES = (size_t)M_DIM * K_DIM;   // 32 MB int8 activations
  char* ws = (char*)d_ws;
  char* wp = ws;
  char* q1 = ws + WP_BYTES;
  char* q2 = q1 + Q_BYTES;
  int* corr = (int*)(q2 + Q_BYTES);
  const size_t NEEDED = WP_BYTES + 2 * Q_BYTES + (size_t)N_DIM * sizeof(int);
  if (ws_size < NEEDED) return;

  pack_w_kernel<<<N_DIM, 256, 0, stream>>>(wq, wp, corr, zp_in);
  quant_in_kernel<<<(M_DIM * K_DIM / 4) / 256, 256, 0, stream>>>(x, q1, s_in, zp_in);

  dim3 grid((M_DIM / 256) * (N_DIM / 256));  // 512 blocks
  dim3 blk(512);
  gemm_kernel<1><<<grid, blk, 0, stream>>>(q1, wp, corr, s_w, bias, s_in, zp_in, q2, nullptr);
  gemm_kernel<1><<<grid, blk, 0, stream>>>(q2, wp, corr, s_w, bias, s_in, zp_in, q1, nullptr);
  gemm_kernel<0><<<grid, blk, 0, stream>>>(q1, wp, corr, s_w, bias, s_in, zp_in, nullptr, out);
}

// Round 12
// 453.127 us; speedup vs baseline: 1.0186x; 1.0186x over previous
//
#include <hip/hip_runtime.h>
#include <stdint.h>

#define M_DIM 8192
#define K_DIM 4096
#define N_DIM 4096
#define KTILES (K_DIM / 64)

typedef __attribute__((ext_vector_type(4))) int i32x4;

// ---------------------------------------------------------------------------
// Pack int32-stored int8 weights [N,K] -> true int8 [N,K]; per-row sum folded
// into integer correction corr[n] = (128 - zp) * rowsum[n].
// ---------------------------------------------------------------------------
__global__ void pack_w_kernel(const int* __restrict__ w, char* __restrict__ wp,
                              int* __restrict__ corr, const int* __restrict__ zpp) {
  __shared__ int red[256];
  const int n = blockIdx.x;
  const int t = threadIdx.x;
  const int4* row = (const int4*)(w + (size_t)n * K_DIM);
  int s = 0;
  int words[4];
#pragma unroll
  for (int u = 0; u < 4; ++u) {
    int4 v = row[t * 4 + u];
    s += v.x + v.y + v.z + v.w;
    words[u] = (v.x & 255) | ((v.y & 255) << 8) | ((v.z & 255) << 16) | (v.w << 24);
  }
  ((int4*)(wp + (size_t)n * K_DIM))[t] = make_int4(words[0], words[1], words[2], words[3]);
  red[t] = s;
  __syncthreads();
  for (int off = 128; off > 0; off >>= 1) {
    if (t < off) red[t] += red[t + off];
    __syncthreads();
  }
  if (t == 0) corr[n] = (128 - zpp[0]) * red[0];
}

// ---------------------------------------------------------------------------
// Quantize fp32 input -> int8 (q - 128), 4 elements/thread.
// ---------------------------------------------------------------------------
__global__ void quant_in_kernel(const float* __restrict__ x, char* __restrict__ q,
                                const float* __restrict__ sp, const int* __restrict__ zpp) {
  const int i = blockIdx.x * blockDim.x + threadIdx.x;
  const float s = sp[0];
  const float zp = (float)zpp[0];
  float4 v = ((const float4*)x)[i];
  float t0 = fminf(fmaxf(rintf(v.x / s) + zp, 0.f), 255.f);
  float t1 = fminf(fmaxf(rintf(v.y / s) + zp, 0.f), 255.f);
  float t2 = fminf(fmaxf(rintf(v.z / s) + zp, 0.f), 255.f);
  float t3 = fminf(fmaxf(rintf(v.w / s) + zp, 0.f), 255.f);
  int b0 = (int)t0 - 128, b1 = (int)t1 - 128, b2 = (int)t2 - 128, b3 = (int)t3 - 128;
  ((int*)q)[i] = (b0 & 255) | ((b1 & 255) << 8) | ((b2 & 255) << 16) | (b3 << 24);
}

// ---------------------------------------------------------------------------
// 256x256 i8 GEMM, 2-slot double buffer -> 64 KB LDS -> TWO independent
// blocks resident per CU. Rationale: R3-R11 all had LDS=128KB -> 1 block/CU
// -> all 8 waves in ONE barrier domain -> nothing covers the per-tile
// drain + read<->MFMA alternation (2540 cyc/tile = LDS + MFMA serial).
// Two mutually-async blocks per CU cover each other's stalls (m114/m97
// mechanism: implicit cross-block overlap, no intra-block cleverness).
// Geometry: 512 thr = 8 waves (2M x 4N), per-wave 128x64, BK=64 B,
// mfma_i32_16x16x64_i8, 32 MFMA/wave/tile. Regs: 128 VGPR + 128 AGPR acc
// = 256/wave x 16 waves/CU = 1024/SIMD <= 2048 (fits).
// Ledger (2-slot, dist 1): tile t reads slot t&1, stages t+1 into t&1^1,
// vmcnt(0)+barrier at tile end, trailing frag reads from the confirmed
// slot. Reads of slot X in tile t-1 end before t-1's barrier -> no race
// with tile t's stage writes to X. Stores only in epilogue.
// Swizzle (0-conflict R1-R11): phys 16B slot = g ^ ((row>>1)&3) on staging
// source and ds_read addr. B content permutation (R8/R9-validated): LDS row
// rho holds weight row (rho&~63)+4*(rho&15)+((rho>>4)&3) -> epilogue n
// consecutive per lane -> packed full-line stores (WRITE_SIZE = 32MB).
// No XCD swizzle (R11: FETCH 98->276MB, hurt). No sched_barrier pins (null).
// ---------------------------------------------------------------------------
#define STAGE16(SRC, DST)                                                     \
  __builtin_amdgcn_global_load_lds(                                           \
      (const __attribute__((address_space(1))) void*)(SRC),                   \
      (__attribute__((address_space(3))) void*)(DST), 16, 0, 0)

#define RD(p) (*(const i32x4*)(p))

// Tile body: SLOT = t&1 (compile-time), KN = (t+1)*64 staging k-byte.
#define TILE2(SLOT, KN, DO_NEXT)                                              \
  {                                                                           \
    const char* cA_ = &lds[SLOT][0][0];                                       \
    char* nA_ = &lds[(SLOT) ^ 1][0][0];                                       \
    char* nB_ = &lds[(SLOT) ^ 1][1][0];                                       \
    i32x4 a1_[4];                                                             \
    _Pragma("unroll") for (int i_ = 0; i_ < 4; ++i_)                          \
        a1_[i_] = RD(cA_ + aoff[4 + i_]);                                     \
    if (DO_NEXT) {                                                            \
      STAGE16(asrc0 + (size_t)(KN), nA_ + o0_);                               \
      STAGE16(asrc1 + (size_t)(KN), nA_ + o1_);                               \
      STAGE16(bsrc0 + (size_t)(KN), nB_ + o0_);                               \
      STAGE16(bsrc1 + (size_t)(KN), nB_ + o1_);                               \
    }                                                                         \
    __builtin_amdgcn_s_setprio(1);                                            \
    _Pragma("unroll") for (int i_ = 0; i_ < 4; ++i_)                          \
        _Pragma("unroll") for (int j_ = 0; j_ < 4; ++j_)                      \
            acc[i_][j_] = __builtin_amdgcn_mfma_i32_16x16x64_i8(              \
                a0[i_], b0[j_], acc[i_][j_], 0, 0, 0);                        \
    __builtin_amdgcn_s_setprio(0);                                            \
    __builtin_amdgcn_s_setprio(1);                                            \
    _Pragma("unroll") for (int i_ = 0; i_ < 4; ++i_)                          \
        _Pragma("unroll") for (int j_ = 0; j_ < 4; ++j_)                      \
            acc[4 + i_][j_] = __builtin_amdgcn_mfma_i32_16x16x64_i8(          \
                a1_[i_], b0[j_], acc[4 + i_][j_], 0, 0, 0);                   \
    __builtin_amdgcn_s_setprio(0);                                            \
    asm volatile("s_waitcnt vmcnt(0)" ::: "memory");                          \
    __builtin_amdgcn_s_barrier();                                             \
    if (DO_NEXT) {                                                            \
      _Pragma("unroll") for (int i_ = 0; i_ < 4; ++i_)                        \
          a0[i_] = RD(nA_ + aoff[i_]);                                        \
      _Pragma("unroll") for (int j_ = 0; j_ < 4; ++j_)                        \
          b0[j_] = RD(nB_ + boff[j_]);                                        \
    }                                                                         \
  }

template <int WRITE_Q>
__global__ __launch_bounds__(512, 2) void gemm_kernel(
    const char* __restrict__ qa, const char* __restrict__ wb,
    const int* __restrict__ corr, const float* __restrict__ swp,
    const float* __restrict__ bias, const float* __restrict__ sp,
    const int* __restrict__ zpp, char* __restrict__ outq, float* __restrict__ outf) {
  __shared__ __align__(16) char lds[2][2][16384];  // 64 KB: 2-slot dbuf
  const int tid = threadIdx.x;
  const int lane = tid & 63;
  const int w = tid >> 6;
  const int wr = w >> 2;   // 0..1 (M)
  const int wc = w & 3;    // 0..3 (N)
  const int bid = blockIdx.x;
  const int bm = bid & 31;  // M/256 = 32, fastest: neighbors share B panel
  const int bn = bid >> 5;  // N/256 = 16
  const char* abase = qa + (size_t)bm * 256 * K_DIM;
  const char* bbase = wb + (size_t)bn * 256 * K_DIM;

  // --- per-thread staging constants (inverse-swizzled global sources) ---
  const int o0_ = tid * 16;
  const int o1_ = 8192 + tid * 16;
  const int r0_ = o0_ >> 6, r1_ = o1_ >> 6;
  const int g0_ = ((o0_ >> 4) & 3) ^ ((r0_ >> 1) & 3);
  const int g1_ = ((o1_ >> 4) & 3) ^ ((r1_ >> 1) & 3);
  const char* asrc0 = abase + (size_t)r0_ * K_DIM + g0_ * 16;
  const char* asrc1 = abase + (size_t)r1_ * K_DIM + g1_ * 16;
  // B content permutation: LDS row rho holds weight row (rho&~63)+4*(rho&15)+((rho>>4)&3)
  const int p0_ = (r0_ & ~63) + 4 * (r0_ & 15) + ((r0_ >> 4) & 3);
  const int p1_ = (r1_ & ~63) + 4 * (r1_ & 15) + ((r1_ >> 4) & 3);
  const char* bsrc0 = bbase + (size_t)p0_ * K_DIM + g0_ * 16;
  const char* bsrc1 = bbase + (size_t)p1_ * K_DIM + g1_ * 16;

  // --- per-thread ds_read byte offsets (swizzled) ---
  const int rr = lane & 15;
  const int g = lane >> 4;
  int aoff[8], boff[4];
#pragma unroll
  for (int i = 0; i < 8; ++i) {
    const int row = wr * 128 + i * 16 + rr;
    aoff[i] = (row << 6) + ((g ^ ((row >> 1) & 3)) << 4);
  }
#pragma unroll
  for (int j = 0; j < 4; ++j) {
    const int row = wc * 64 + j * 16 + rr;
    boff[j] = (row << 6) + ((g ^ ((row >> 1) & 3)) << 4);
  }

  i32x4 acc[8][4] = {};

  // --- prologue: stage slot 0 (tile 0); drain; read tile-0 frags ---
  STAGE16(asrc0, &lds[0][0][o0_]); STAGE16(asrc1, &lds[0][0][o1_]);
  STAGE16(bsrc0, &lds[0][1][o0_]); STAGE16(bsrc1, &lds[0][1][o1_]);
  asm volatile("s_waitcnt vmcnt(0)" ::: "memory");
  __builtin_amdgcn_s_barrier();

  i32x4 a0[4], b0[4];
#pragma unroll
  for (int i = 0; i < 4; ++i) a0[i] = RD(&lds[0][0][0] + aoff[i]);
#pragma unroll
  for (int j = 0; j < 4; ++j) b0[j] = RD(&lds[0][1][0] + boff[j]);

  // --- main loop: tiles 0..61 in pairs; tail tiles 62, 63 ---
  for (int tb = 0; tb < (KTILES - 2) / 2; ++tb) {
    const size_t k0 = (size_t)(tb * 2 + 1) * 64;
    TILE2(0, k0, 1)
    TILE2(1, k0 + 64, 1)
  }
  TILE2(0, (size_t)(KTILES - 1) * 64, 1)  // tile 62, stages tile 63
  TILE2(1, 0, 0)                          // tile 63, no stage, no next read

  // --- epilogue (R9-validated): frag j, lane c -> n = nb4 + j ---
  const float s = sp[0];
  const float zpf = (float)zpp[0];
  const int m0 = bm * 256 + wr * 128 + (lane >> 4) * 4;
  const int nb4 = bn * 256 + wc * 64 + ((lane & 15) << 2);
  const int4 cr4 = *(const int4*)(corr + nb4);
  const float4 sw4 = *(const float4*)(swp + nb4);
  const float4 bb4 = *(const float4*)(bias + nb4);
  const float fs0 = s * sw4.x, fs1 = s * sw4.y, fs2 = s * sw4.z, fs3 = s * sw4.w;
#pragma unroll
  for (int i = 0; i < 8; ++i) {
#pragma unroll
    for (int q = 0; q < 4; ++q) {
      const int m = m0 + i * 16 + q;
      const float v0 = fs0 * (float)(acc[i][0][q] + cr4.x) + bb4.x;
      const float v1 = fs1 * (float)(acc[i][1][q] + cr4.y) + bb4.y;
      const float v2 = fs2 * (float)(acc[i][2][q] + cr4.z) + bb4.z;
      const float v3 = fs3 * (float)(acc[i][3][q] + cr4.w) + bb4.w;
      if (WRITE_Q) {
        const int b0i = (int)fminf(fmaxf(rintf(v0 / s) + zpf, 0.f), 255.f) - 128;
        const int b1i = (int)fminf(fmaxf(rintf(v1 / s) + zpf, 0.f), 255.f) - 128;
        const int b2i = (int)fminf(fmaxf(rintf(v2 / s) + zpf, 0.f), 255.f) - 128;
        const int b3i = (int)fminf(fmaxf(rintf(v3 / s) + zpf, 0.f), 255.f) - 128;
        const uint32_t pk = (uint32_t)(b0i & 255) | ((uint32_t)(b1i & 255) << 8) |
                            ((uint32_t)(b2i & 255) << 16) | ((uint32_t)b3i << 24);
        *(uint32_t*)(outq + (size_t)m * N_DIM + nb4) = pk;
      } else {
        float4 o4;
        o4.x = v0; o4.y = v1; o4.z = v2; o4.w = v3;
        *(float4*)(outf + (size_t)m * N_DIM + nb4) = o4;
      }
    }
  }
}

// ---------------------------------------------------------------------------
extern "C" void kernel_launch(void* const* d_in, const int* in_sizes, int n_in,
                              void* d_out, int out_size, void* d_ws, size_t ws_size,
                              hipStream_t stream) {
  const float* x = (const float*)d_in[0];
  const int* wq = (const int*)d_in[1];
  const float* bias = (const float*)d_in[2];
  const float* s_in = (const float*)d_in[3];
  const int* zp_in = (const int*)d_in[4];
  const float* s_w = (const float*)d_in[5];
  float* out = (float*)d_out;

  const size_t WP_BYTES = (size_t)N_DIM * K_DIM;  // 16 MB packed int8 W
  const size_t Q_BYTES = (size_t)M_DIM * K_DIM;   // 32 MB int8 activations
  char* ws = (char*)d_ws;
  char* wp = ws;
  char* q1 = ws + WP_BYTES;
  char* q2 = q1 + Q_BYTES;
  int* corr = (int*)(q2 + Q_BYTES);
  const size_t NEEDED = WP_BYTES + 2 * Q_BYTES + (size_t)N_DIM * sizeof(int);
  if (ws_size < NEEDED) return;

  pack_w_kernel<<<N_DIM, 256, 0, stream>>>(wq, wp, corr, zp_in);
  quant_in_kernel<<<(M_DIM * K_DIM / 4) / 256, 256, 0, stream>>>(x, q1, s_in, zp_in);

  dim3 grid((M_DIM / 256) * (N_DIM / 256));  // 512 blocks
  dim3 blk(512);
  gemm_kernel<1><<<grid, blk, 0, stream>>>(q1, wp, corr, s_w, bias, s_in, zp_in, q2, nullptr);
  gemm_kernel<1><<<grid, blk, 0, stream>>>(q2, wp, corr, s_w, bias, s_in, zp_in, q1, nullptr);
  gemm_kernel<0><<<grid, blk, 0, stream>>>(q1, wp, corr, s_w, bias, s_in, zp_in, nullptr, out);
}